// Round 1
// baseline (2209.996 us; speedup 1.0000x reference)
//
#include <hip/hip_runtime.h>
#include <cmath>

// Problem constants (reference: B,T,D,H = 4096,48,64,128)
#define Bb 4096
#define Tt 48
#define Dd 64
#define Hh 128
#define NB 16      // batch rows per block
#define NTHR 512   // threads per block (8 waves)

// ---- workspace float offsets ----
// denoms[48] | loss_acc | pad | transposed weights
#define WS_DEN   0
#define WS_LOSS  48
#define WS_TDH   64                    // [64][128]   gamma_h weights, WT[k][jh]
#define WS_DIAG  (WS_TDH + 8192)       // [64]        diag(W_td_x)
#define WS_HIST  (WS_DIAG + 64)        // [128][64]   WT[k][j]
#define WS_FEAT  (WS_HIST + 8192)      // [64][64]    WT[k][j], diag zeroed
#define WS_COMB  (WS_FEAT + 4096)      // [128][64]   WT[k][j]
#define WS_IH    (WS_COMB + 8192)      // [128][128][4] float4 per (k,jh), gates i,f,g,o
#define WS_HH    (WS_IH + 65536)       // [128][128][4]
#define WS_TOTAL (WS_HH + 65536)       // ~160K floats = 640 KB

__device__ __forceinline__ float sigmoidf_(float x) {
  return 1.0f / (1.0f + __expf(-x));
}
__device__ __forceinline__ float tanhf_(float x) {
  // tanh(x) = 2*sigmoid(2x)-1 ; correct limits at +-inf via __expf -> 0/inf
  return 2.0f / (1.0f + __expf(-2.0f * x)) - 1.0f;
}

// ---------------- kernel 0: transpose/pack weights, zero accumulators ----------------
__global__ void prep_kernel(const float* __restrict__ W_td_h, const float* __restrict__ W_td_x,
                            const float* __restrict__ W_hist, const float* __restrict__ W_feat,
                            const float* __restrict__ W_comb, const float* __restrict__ W_ih,
                            const float* __restrict__ W_hh, float* __restrict__ ws) {
  int idx = blockIdx.x * blockDim.x + threadIdx.x;
  int stride = gridDim.x * blockDim.x;
  for (int i = idx; i < 49; i += stride) ws[i] = 0.0f;  // denoms[48] + loss_acc
  for (int i = idx; i < 8192; i += stride) {            // WT_td_h[k][jh] = W_td_h[jh][k]
    int k = i >> 7, jh = i & 127;
    ws[WS_TDH + i] = W_td_h[jh * 64 + k];
  }
  for (int i = idx; i < 64; i += stride) ws[WS_DIAG + i] = W_td_x[i * 64 + i];
  for (int i = idx; i < 8192; i += stride) {            // WT_hist[k][j] = W_hist[j][k]
    int k = i >> 6, j = i & 63;
    ws[WS_HIST + i] = W_hist[j * 128 + k];
  }
  for (int i = idx; i < 4096; i += stride) {            // WT_feat[k][j], diag zeroed
    int k = i >> 6, j = i & 63;
    ws[WS_FEAT + i] = (j == k) ? 0.0f : W_feat[j * 64 + k];
  }
  for (int i = idx; i < 8192; i += stride) {            // WT_comb[k][j] = W_comb[j][k]
    int k = i >> 6, j = i & 63;
    ws[WS_COMB + i] = W_comb[j * 128 + k];
  }
  for (int i = idx; i < 65536; i += stride) {           // gates interleaved float4 per (k,jh)
    int g = i & 3, jh = (i >> 2) & 127, k = i >> 9;
    ws[WS_IH + i] = W_ih[(g * 128 + jh) * 128 + k];
    ws[WS_HH + i] = W_hh[(g * 128 + jh) * 128 + k];
  }
}

// ---------------- kernel 1: denom_t = sum over [B,D] of masks[:,t,:] ----------------
__global__ void denom_kernel(const float* __restrict__ masks, float* __restrict__ ws) {
  int t = blockIdx.x >> 4;          // 48 t-values
  int chunk = blockIdx.x & 15;      // 16 chunks of 256 batch rows
  int base = chunk * 256;
  int tid = threadIdx.x;
  int j = tid & 63;
  int brow = tid >> 6;              // 0..3
  float s = 0.0f;
  for (int i = 0; i < 64; i++) {
    int b = base + i * 4 + brow;
    s += masks[((size_t)b * Tt + t) * Dd + j];
  }
  for (int off = 32; off > 0; off >>= 1) s += __shfl_down(s, off, 64);
  __shared__ float red[4];
  if ((tid & 63) == 0) red[tid >> 6] = s;
  __syncthreads();
  if (tid == 0) atomicAdd(&ws[WS_DEN + t], red[0] + red[1] + red[2] + red[3]);
}

// ---------------- kernel 2: persistent recurrence ----------------
__global__ __launch_bounds__(NTHR, 2)
void main_kernel(const float* __restrict__ values, const float* __restrict__ masks,
                 const float* __restrict__ deltas,
                 const float* __restrict__ b_td_h, const float* __restrict__ b_td_x,
                 const float* __restrict__ b_hist, const float* __restrict__ b_feat,
                 const float* __restrict__ b_comb,
                 const float* __restrict__ b_ih, const float* __restrict__ b_hh,
                 float* ws, float* __restrict__ out) {
  __shared__ float sh[NB * Hh];                       // decayed/updated hidden state
  __shared__ float sxt[NB * Dd], smt[NB * Dd], sdt[NB * Dd];
  __shared__ float sxh[NB * Dd], sxc[NB * Dd], szh[NB * Dd], sgx[NB * Dd], scc[NB * Dd];
  __shared__ float red[8];

  int tid = threadIdx.x;
  int b0 = blockIdx.x * NB;

  for (int i = tid; i < NB * Hh; i += NTHR) sh[i] = 0.0f;

  // ---- per-thread fixed mappings ----
  // Stage A/F mapping: (jh, fbrow) -> 4 batch rows fbrow+4i
  int jh = tid & 127;
  int fbrow = tid >> 7;                                // 0..3
  // Stage B/C/E mapping: (j, brow8) -> 2 batch rows brow8, brow8+8
  int j = tid & 63;
  int brow8 = tid >> 6;                                // 0..7

  float c_reg[4] = {0.f, 0.f, 0.f, 0.f};               // LSTM cell state, this thread's 4 rows
  float bias_i = b_ih[jh]        + b_hh[jh];
  float bias_f = b_ih[128 + jh]  + b_hh[128 + jh];
  float bias_g = b_ih[256 + jh]  + b_hh[256 + jh];
  float bias_o = b_ih[384 + jh]  + b_hh[384 + jh];
  float btdh  = b_td_h[jh];
  float bhist = b_hist[j], bfeat = b_feat[j], bcomb = b_comb[j];
  // gamma_x mapping: 2 consecutive elements per thread
  int ge = tid * 2;
  int gj = ge & 63;
  float diag0 = ws[WS_DIAG + gj],  diag1 = ws[WS_DIAG + gj + 1];
  float btx0  = b_td_x[gj],        btx1  = b_td_x[gj + 1];

  float loss_acc = 0.0f;
  float* imp = out + 1;                                // imputations follow the scalar loss

  for (int t = 0; t < Tt; t++) {
    __syncthreads();
    // ---- load x, m, d tiles (float2 per thread per array, coalesced) ----
    {
      int e = tid * 2;
      int lb = e >> 6, li = e & 63;
      size_t g = ((size_t)(b0 + lb) * Tt + t) * Dd + li;
      float2 v = *(const float2*)(values + g);
      float2 m = *(const float2*)(masks + g);
      float2 d = *(const float2*)(deltas + g);
      sxt[e] = v.x; sxt[e + 1] = v.y;
      smt[e] = m.x; smt[e + 1] = m.y;
      sdt[e] = d.x; sdt[e + 1] = d.y;
    }
    float invden = 1.0f / (ws[WS_DEN + t] + 1e-5f);
    __syncthreads();

    // ---- Stage A: gamma_h decay of h; gamma_x ----
    {
      float a0 = btdh, a1 = btdh, a2 = btdh, a3 = btdh;
      const float* wt = ws + WS_TDH;
      #pragma unroll 8
      for (int k = 0; k < 64; k++) {
        float w = wt[k * 128 + jh];
        a0 += sdt[(fbrow)*64 + k] * w;
        a1 += sdt[(fbrow + 4) * 64 + k] * w;
        a2 += sdt[(fbrow + 8) * 64 + k] * w;
        a3 += sdt[(fbrow + 12) * 64 + k] * w;
      }
      sh[(fbrow)*128 + jh]      *= __expf(-fmaxf(a0, 0.0f));
      sh[(fbrow + 4) * 128 + jh]  *= __expf(-fmaxf(a1, 0.0f));
      sh[(fbrow + 8) * 128 + jh]  *= __expf(-fmaxf(a2, 0.0f));
      sh[(fbrow + 12) * 128 + jh] *= __expf(-fmaxf(a3, 0.0f));
      sgx[ge]     = __expf(-fmaxf(sdt[ge] * diag0 + btx0, 0.0f));
      sgx[ge + 1] = __expf(-fmaxf(sdt[ge + 1] * diag1 + btx1, 0.0f));
    }
    __syncthreads();

    // ---- Stage B: x_h = h @ W_hist^T + b; loss1; x_c ----
    {
      float a0 = bhist, a1 = bhist;
      const float* wt = ws + WS_HIST;
      int bA = brow8, bB = brow8 + 8;
      #pragma unroll 8
      for (int k = 0; k < 128; k++) {
        float w = wt[k * 64 + j];
        a0 += sh[bA * 128 + k] * w;
        a1 += sh[bB * 128 + k] * w;
      }
      int iA = bA * 64 + j, iB = bB * 64 + j;
      float xA = sxt[iA], mA = smt[iA], xB = sxt[iB], mB = smt[iB];
      loss_acc += (fabsf(xA - a0) * mA + fabsf(xB - a1) * mB) * invden;
      sxh[iA] = a0; sxh[iB] = a1;
      sxc[iA] = mA * xA + (1.0f - mA) * a0;
      sxc[iB] = mB * xB + (1.0f - mB) * a1;
    }
    __syncthreads();

    // ---- Stage C: z_h = x_c @ W_feat_m^T + b; loss2 ----
    {
      float a0 = bfeat, a1 = bfeat;
      const float* wt = ws + WS_FEAT;
      int bA = brow8, bB = brow8 + 8;
      #pragma unroll 8
      for (int k = 0; k < 64; k++) {
        float w = wt[k * 64 + j];
        a0 += sxc[bA * 64 + k] * w;
        a1 += sxc[bB * 64 + k] * w;
      }
      int iA = bA * 64 + j, iB = bB * 64 + j;
      float xA = sxt[iA], mA = smt[iA], xB = sxt[iB], mB = smt[iB];
      loss_acc += (fabsf(xA - a0) * mA + fabsf(xB - a1) * mB) * invden;
      szh[iA] = a0; szh[iB] = a1;
    }
    __syncthreads();

    // ---- Stage E: alpha = [gamma_x, m] @ W_comb^T + b; c_h; loss3; c_c -> out ----
    {
      float a0 = bcomb, a1 = bcomb;
      const float* wt = ws + WS_COMB;
      int bA = brow8, bB = brow8 + 8;
      #pragma unroll 8
      for (int k = 0; k < 64; k++) {
        float w = wt[k * 64 + j];
        a0 += sgx[bA * 64 + k] * w;
        a1 += sgx[bB * 64 + k] * w;
      }
      #pragma unroll 8
      for (int k = 0; k < 64; k++) {
        float w = wt[(64 + k) * 64 + j];
        a0 += smt[bA * 64 + k] * w;
        a1 += smt[bB * 64 + k] * w;
      }
      int iA = bA * 64 + j, iB = bB * 64 + j;
      float xA = sxt[iA], mA = smt[iA], xB = sxt[iB], mB = smt[iB];
      float chA = a0 * szh[iA] + (1.0f - a0) * sxh[iA];
      float chB = a1 * szh[iB] + (1.0f - a1) * sxh[iB];
      loss_acc += (fabsf(xA - chA) * mA + fabsf(xB - chB) * mB) * invden;
      float ccA = mA * xA + (1.0f - mA) * chA;
      float ccB = mB * xB + (1.0f - mB) * chB;
      scc[iA] = ccA; scc[iB] = ccB;
      imp[((size_t)(b0 + bA) * Tt + t) * Dd + j] = ccA;
      imp[((size_t)(b0 + bB) * Tt + t) * Dd + j] = ccB;
    }
    __syncthreads();

    // ---- Stage F: gates = [c_c,m] @ W_ih^T + h @ W_hh^T + b; LSTM update ----
    {
      float4 acc[4];
      #pragma unroll
      for (int i = 0; i < 4; i++) { acc[i].x = bias_i; acc[i].y = bias_f; acc[i].z = bias_g; acc[i].w = bias_o; }
      const float4* wih = (const float4*)(ws + WS_IH);
      const float4* whh = (const float4*)(ws + WS_HH);
      #pragma unroll 4
      for (int k = 0; k < 64; k++) {                   // input part 1: c_c
        float4 w = wih[k * 128 + jh];
        #pragma unroll
        for (int i = 0; i < 4; i++) {
          float a = scc[(fbrow + 4 * i) * 64 + k];
          acc[i].x += a * w.x; acc[i].y += a * w.y; acc[i].z += a * w.z; acc[i].w += a * w.w;
        }
      }
      #pragma unroll 4
      for (int k = 0; k < 64; k++) {                   // input part 2: m
        float4 w = wih[(64 + k) * 128 + jh];
        #pragma unroll
        for (int i = 0; i < 4; i++) {
          float a = smt[(fbrow + 4 * i) * 64 + k];
          acc[i].x += a * w.x; acc[i].y += a * w.y; acc[i].z += a * w.z; acc[i].w += a * w.w;
        }
      }
      #pragma unroll 4
      for (int k = 0; k < 128; k++) {                  // hidden part
        float4 w = whh[k * 128 + jh];
        #pragma unroll
        for (int i = 0; i < 4; i++) {
          float a = sh[(fbrow + 4 * i) * 128 + k];
          acc[i].x += a * w.x; acc[i].y += a * w.y; acc[i].z += a * w.z; acc[i].w += a * w.w;
        }
      }
      __syncthreads();                                 // all reads of sh done before writes
      #pragma unroll
      for (int i = 0; i < 4; i++) {
        float ig = sigmoidf_(acc[i].x);
        float fg = sigmoidf_(acc[i].y);
        float gg = tanhf_(acc[i].z);
        float og = sigmoidf_(acc[i].w);
        c_reg[i] = fg * c_reg[i] + ig * gg;
        sh[(fbrow + 4 * i) * 128 + jh] = og * tanhf_(c_reg[i]);
      }
    }
  }

  // ---- loss reduction: wave shuffle -> LDS -> one atomic per block ----
  float s = loss_acc;
  for (int off = 32; off > 0; off >>= 1) s += __shfl_down(s, off, 64);
  if ((tid & 63) == 0) red[tid >> 6] = s;
  __syncthreads();
  if (tid == 0) {
    float tot = 0.0f;
    #pragma unroll
    for (int w = 0; w < 8; w++) tot += red[w];
    atomicAdd(&ws[WS_LOSS], tot);
  }
}

// ---------------- kernel 3: finalize loss ----------------
__global__ void final_kernel(const float* __restrict__ ws, float* __restrict__ out) {
  if (threadIdx.x == 0 && blockIdx.x == 0) out[0] = 0.3f * ws[WS_LOSS];
}

extern "C" void kernel_launch(void* const* d_in, const int* in_sizes, int n_in,
                              void* d_out, int out_size, void* d_ws, size_t ws_size,
                              hipStream_t stream) {
  const float* values = (const float*)d_in[0];
  const float* masks  = (const float*)d_in[1];
  const float* deltas = (const float*)d_in[2];
  const float* W_td_h = (const float*)d_in[3];
  const float* b_td_h = (const float*)d_in[4];
  const float* W_td_x = (const float*)d_in[5];
  const float* b_td_x = (const float*)d_in[6];
  const float* W_hist = (const float*)d_in[7];
  const float* b_hist = (const float*)d_in[8];
  const float* W_feat = (const float*)d_in[9];
  const float* b_feat = (const float*)d_in[10];
  const float* W_comb = (const float*)d_in[11];
  const float* b_comb = (const float*)d_in[12];
  const float* W_ih   = (const float*)d_in[13];
  const float* W_hh   = (const float*)d_in[14];
  const float* b_ih   = (const float*)d_in[15];
  const float* b_hh   = (const float*)d_in[16];
  float* out = (float*)d_out;
  float* ws  = (float*)d_ws;   // needs WS_TOTAL*4 = ~640 KB

  prep_kernel<<<dim3(64), dim3(256), 0, stream>>>(W_td_h, W_td_x, W_hist, W_feat,
                                                  W_comb, W_ih, W_hh, ws);
  denom_kernel<<<dim3(48 * 16), dim3(256), 0, stream>>>(masks, ws);
  main_kernel<<<dim3(Bb / NB), dim3(NTHR), 0, stream>>>(values, masks, deltas,
                                                        b_td_h, b_td_x, b_hist, b_feat,
                                                        b_comb, b_ih, b_hh, ws, out);
  final_kernel<<<dim3(1), dim3(64), 0, stream>>>(ws, out);
}

// Round 2
// 376.559 us; speedup vs baseline: 5.8689x; 5.8689x over previous
//
#include <hip/hip_runtime.h>
#include <cmath>

// B,T,D,H = 4096,48,64,128
#define Bb 4096
#define Tt 48
#define Dd 64
#define Hh 128
#define NB 16      // batch rows per block (M of MFMA)
#define NTHR 512   // 8 waves

typedef unsigned short ushort_t;
typedef __attribute__((ext_vector_type(8))) short short8;    // 8 bf16 = 4 VGPRs (MFMA A/B frag)
typedef __attribute__((ext_vector_type(4))) float floatx4;   // MFMA C/D frag
typedef __attribute__((ext_vector_type(4))) unsigned int uintx4;

// ---- workspace layout (floats) ----
#define WS_DEN   0     // denoms[48]
#define WS_LOSS  48
#define WS_FRAGS 64    // bf16 frag area starts here (16B aligned)
// frag indices (each frag = 64 lanes x 8 bf16 = 512 ushorts = 1 KB)
#define FR_F 0         // 256 frags: gates  [w:8][g:4][ks:8]   K=256 (c_c|m|h)
#define FR_A 256       // 16: W_td_h        [w:8][ks:2]        K=64
#define FR_B 272       // 16: W_hist        [w:4][ks:4]        K=128
#define FR_C 288       // 8 : W_feat masked [w:4][ks:2]        K=64
#define FR_E 296       // 16: W_comb        [w:4][ks:4]        K=128
#define N_FRAGS 312

__device__ __forceinline__ ushort_t f2bf(float x) {   // RNE float->bf16 bits
  unsigned int u = __float_as_uint(x);
  u += 0x7fffu + ((u >> 16) & 1u);
  return (ushort_t)(u >> 16);
}
__device__ __forceinline__ float sigmoidf_(float x) { return 1.0f / (1.0f + __expf(-x)); }
__device__ __forceinline__ float tanhf_(float x) { return 2.0f / (1.0f + __expf(-2.0f * x)) - 1.0f; }

// ---------------- kernel 0: pack weights into per-lane MFMA B-frags (bf16) ----------------
// B-frag layout for mfma_f32_16x16x32_bf16: lane l holds B[k=(l>>4)*8+j][n=l&15], j=0..7
__global__ void prep_kernel(const float* __restrict__ W_td_h, const float* __restrict__ W_hist,
                            const float* __restrict__ W_feat, const float* __restrict__ W_comb,
                            const float* __restrict__ W_ih, const float* __restrict__ W_hh,
                            float* __restrict__ ws) {
  int f = blockIdx.x;                 // one frag per block
  int tid = threadIdx.x;              // 256 threads, 2 elems each
  if (f == 0 && tid < 64) ws[tid] = 0.0f;   // zero denoms + loss
  ushort_t* fb = (ushort_t*)(ws + WS_FRAGS);
  #pragma unroll
  for (int u = 0; u < 2; u++) {
    int e = tid * 2 + u;              // 0..511 = l*8 + j
    int l = e >> 3, j = e & 7;
    int n16 = l & 15;
    int kq = ((l >> 4) << 3) + j;     // quad*8 + j  (0..31)
    float v;
    if (f < 256) {
      int w = f >> 5, g = (f >> 3) & 3, ks = f & 7;
      int n = g * 128 + w * 16 + n16;           // gate row in [512]
      int k = ks * 32 + kq;                     // 0..255: 0-127 -> W_ih, 128-255 -> W_hh
      v = (k < 128) ? W_ih[n * 128 + k] : W_hh[n * 128 + (k - 128)];
    } else if (f < 272) {
      int ff = f - 256, w = ff >> 1, ks = ff & 1;
      int n = w * 16 + n16;                     // 0..127
      v = W_td_h[n * 64 + ks * 32 + kq];
    } else if (f < 288) {
      int ff = f - 272, w = ff >> 2, ks = ff & 3;
      int n = w * 16 + n16;                     // 0..63
      v = W_hist[n * 128 + ks * 32 + kq];
    } else if (f < 296) {
      int ff = f - 288, w = ff >> 1, ks = ff & 1;
      int n = w * 16 + n16;
      int k = ks * 32 + kq;
      v = (n == k) ? 0.0f : W_feat[n * 64 + k];  // zeroed diagonal
    } else {
      int ff = f - 296, w = ff >> 2, ks = ff & 3;
      int n = w * 16 + n16;
      v = W_comb[n * 128 + ks * 32 + kq];       // cols: 0-63 gamma_x, 64-127 m
    }
    fb[f * 512 + e] = f2bf(v);
  }
}

// ---------------- kernel 1: denom_t = sum over [B,D] of masks[:,t,:] ----------------
__global__ void denom_kernel(const float* __restrict__ masks, float* __restrict__ ws) {
  int t = blockIdx.x >> 4;
  int chunk = blockIdx.x & 15;
  int base = chunk * 256;
  int tid = threadIdx.x;
  int j = tid & 63;
  int brow = tid >> 6;
  float s = 0.0f;
  for (int i = 0; i < 64; i++) {
    int b = base + i * 4 + brow;
    s += masks[((size_t)b * Tt + t) * Dd + j];
  }
  for (int off = 32; off > 0; off >>= 1) s += __shfl_down(s, off, 64);
  __shared__ float red[4];
  if ((tid & 63) == 0) red[tid >> 6] = s;
  __syncthreads();
  if (tid == 0) atomicAdd(&ws[WS_DEN + t], red[0] + red[1] + red[2] + red[3]);
}

// ---------------- kernel 2: persistent MFMA recurrence ----------------
__global__ __launch_bounds__(NTHR, 2)
void main_kernel(const float* __restrict__ values, const float* __restrict__ masks,
                 const float* __restrict__ deltas, const float* __restrict__ W_td_x,
                 const float* __restrict__ b_td_h, const float* __restrict__ b_td_x,
                 const float* __restrict__ b_hist, const float* __restrict__ b_feat,
                 const float* __restrict__ b_comb,
                 const float* __restrict__ b_ih, const float* __restrict__ b_hh,
                 float* ws, float* __restrict__ out) {
  // LDS (~59 KB). Row strides padded to keep ds_read_b128 16B-aligned + bank-shifted.
  __shared__ __align__(16) ushort_t act[16 * 264];   // bf16 [16][256+8]: 0-63 c_c | 64-127 m | 128-255 h_dec
  __shared__ __align__(16) ushort_t dbuf[16 * 72];   // bf16 d
  __shared__ __align__(16) ushort_t gmbuf[16 * 136]; // bf16 [gamma_x | m]
  __shared__ __align__(16) ushort_t xcbuf[16 * 72];  // bf16 x_c
  __shared__ __align__(16) float xbuf[16 * 68];
  __shared__ __align__(16) float mbuf[16 * 68];
  __shared__ __align__(16) float xhbuf[16 * 68];
  __shared__ __align__(16) float zhbuf[16 * 68];
  __shared__ __align__(16) ushort_t fragA[16 * 512]; // LDS-resident W_td_h frags
  __shared__ __align__(16) ushort_t fragC[8 * 512];  // LDS-resident W_feat frags
  __shared__ float red[8];

  int tid = threadIdx.x;
  int w = tid >> 6;            // wave 0..7
  int lane = tid & 63;
  int l15 = lane & 15;
  int quad = lane >> 4;
  int b0 = blockIdx.x * NB;
  const ushort_t* fb = (const ushort_t*)(ws + WS_FRAGS);

  // ---- one-time: copy A/C weight frags to LDS ----
  {
    const uintx4* srcA = (const uintx4*)(fb + FR_A * 512);
    uintx4* dstA = (uintx4*)fragA;
    for (int i = tid; i < 1024; i += NTHR) dstA[i] = srcA[i];
    const uintx4* srcC = (const uintx4*)(fb + FR_C * 512);
    uintx4* dstC = (uintx4*)fragC;
    for (int i = tid; i < 512; i += NTHR) dstC[i] = srcC[i];
  }

  // ---- one-time: gate weights (and B/E weights) into registers ----
  short8 wF[32];
  #pragma unroll
  for (int g = 0; g < 4; g++)
    #pragma unroll
    for (int ks = 0; ks < 8; ks++)
      wF[g * 8 + ks] = *(const short8*)(fb + (size_t)(FR_F + w * 32 + g * 8 + ks) * 512 + lane * 8);
  short8 wBE[4];
  if (w < 4) {
    #pragma unroll
    for (int ks = 0; ks < 4; ks++)
      wBE[ks] = *(const short8*)(fb + (size_t)(FR_B + w * 4 + ks) * 512 + lane * 8);
  } else {
    #pragma unroll
    for (int ks = 0; ks < 4; ks++)
      wBE[ks] = *(const short8*)(fb + (size_t)(FR_E + (w - 4) * 4 + ks) * 512 + lane * 8);
  }

  // ---- biases at this lane's owned columns ----
  int colh = w * 16 + l15;           // 0..127 (stage A cols, F gate cols)
  float biasF0 = b_ih[colh]       + b_hh[colh];
  float biasF1 = b_ih[128 + colh] + b_hh[128 + colh];
  float biasF2 = b_ih[256 + colh] + b_hh[256 + colh];
  float biasF3 = b_ih[384 + colh] + b_hh[384 + colh];
  float biasA  = b_td_h[colh];
  int colD = (w & 3) * 16 + l15;     // 0..63 (stage B/C/E cols)
  float biasBE = (w < 4) ? b_hist[colD] : b_comb[colD];
  float biasC  = b_feat[colD];

  // ---- input-load mapping (2 consecutive elements per thread) ----
  int e0 = tid * 2;
  int lb = e0 >> 6, li = e0 & 63;
  size_t gbase = ((size_t)(b0 + lb) * Tt) * Dd + li;
  float diag0 = W_td_x[li * 64 + li], diag1 = W_td_x[(li + 1) * 64 + (li + 1)];
  float btx0 = b_td_x[li], btx1 = b_td_x[li + 1];

  float h_reg[4] = {0.f, 0.f, 0.f, 0.f};   // h at (m=quad*4+r, n=colh) — same lane owns it in A and F
  float c_reg[4] = {0.f, 0.f, 0.f, 0.f};
  float loss_acc = 0.0f;
  float* imp = out + 1;

  for (int t = 0; t < Tt; t++) {
    __syncthreads();                               // prev step's F reads of act done
    // ---- load x,m,d; write fp32 + bf16 staging; gamma_x elementwise ----
    {
      size_t g = gbase + (size_t)t * Dd;
      float2 xv = *(const float2*)(values + g);
      float2 mv = *(const float2*)(masks + g);
      float2 dv = *(const float2*)(deltas + g);
      xbuf[lb * 68 + li] = xv.x; xbuf[lb * 68 + li + 1] = xv.y;
      mbuf[lb * 68 + li] = mv.x; mbuf[lb * 68 + li + 1] = mv.y;
      unsigned int mpk = (unsigned int)f2bf(mv.x) | ((unsigned int)f2bf(mv.y) << 16);
      *(unsigned int*)(&act[lb * 264 + 64 + li]) = mpk;
      *(unsigned int*)(&gmbuf[lb * 136 + 64 + li]) = mpk;
      *(unsigned int*)(&dbuf[lb * 72 + li]) =
          (unsigned int)f2bf(dv.x) | ((unsigned int)f2bf(dv.y) << 16);
      float g0 = __expf(-fmaxf(dv.x * diag0 + btx0, 0.0f));
      float g1 = __expf(-fmaxf(dv.y * diag1 + btx1, 0.0f));
      *(unsigned int*)(&gmbuf[lb * 136 + li]) =
          (unsigned int)f2bf(g0) | ((unsigned int)f2bf(g1) << 16);
    }
    float invden = 1.0f / (ws[WS_DEN + t] + 1e-5f);
    __syncthreads();

    // ---- Stage A: gamma_h = exp(-relu(d @ W_td_h^T + b)); decay h; stage h_dec bf16 ----
    {
      floatx4 acc = {biasA, biasA, biasA, biasA};
      #pragma unroll
      for (int ks = 0; ks < 2; ks++) {
        short8 a = *(const short8*)(&dbuf[l15 * 72 + ks * 32 + quad * 8]);
        short8 b = *(const short8*)(&fragA[(size_t)(w * 2 + ks) * 512 + lane * 8]);
        acc = __builtin_amdgcn_mfma_f32_16x16x32_bf16(a, b, acc, 0, 0, 0);
      }
      #pragma unroll
      for (int r = 0; r < 4; r++) {
        int m = quad * 4 + r;
        h_reg[r] *= __expf(-fmaxf(acc[r], 0.0f));
        act[m * 264 + 128 + colh] = f2bf(h_reg[r]);
      }
    }
    __syncthreads();

    // ---- Stage B (waves 0-3): x_h = h_dec @ W_hist^T + b; loss1; x_c ----
    // ---- Stage E-mat (waves 4-7): alpha = [gamma_x,m] @ W_comb^T + b (held in regs) ----
    floatx4 accP = {biasBE, biasBE, biasBE, biasBE};
    if (w < 4) {
      #pragma unroll
      for (int ks = 0; ks < 4; ks++) {
        short8 a = *(const short8*)(&act[l15 * 264 + 128 + ks * 32 + quad * 8]);
        accP = __builtin_amdgcn_mfma_f32_16x16x32_bf16(a, wBE[ks], accP, 0, 0, 0);
      }
      #pragma unroll
      for (int r = 0; r < 4; r++) {
        int m = quad * 4 + r;
        int ix = m * 68 + colD;
        float xh = accP[r];
        float xx = xbuf[ix], mm = mbuf[ix];
        loss_acc += fabsf(xx - xh) * mm * invden;
        xhbuf[ix] = xh;
        xcbuf[m * 72 + colD] = f2bf(mm * xx + (1.0f - mm) * xh);
      }
    } else {
      #pragma unroll
      for (int ks = 0; ks < 4; ks++) {
        short8 a = *(const short8*)(&gmbuf[l15 * 136 + ks * 32 + quad * 8]);
        accP = __builtin_amdgcn_mfma_f32_16x16x32_bf16(a, wBE[ks], accP, 0, 0, 0);
      }
    }
    __syncthreads();

    // ---- Stage C (waves 0-3): z_h = x_c @ W_featM^T + b; loss2 ----
    if (w < 4) {
      floatx4 acc = {biasC, biasC, biasC, biasC};
      #pragma unroll
      for (int ks = 0; ks < 2; ks++) {
        short8 a = *(const short8*)(&xcbuf[l15 * 72 + ks * 32 + quad * 8]);
        short8 b = *(const short8*)(&fragC[(size_t)(w * 2 + ks) * 512 + lane * 8]);
        acc = __builtin_amdgcn_mfma_f32_16x16x32_bf16(a, b, acc, 0, 0, 0);
      }
      #pragma unroll
      for (int r = 0; r < 4; r++) {
        int m = quad * 4 + r;
        int ix = m * 68 + colD;
        float zh = acc[r];
        loss_acc += fabsf(xbuf[ix] - zh) * mbuf[ix] * invden;
        zhbuf[ix] = zh;
      }
    }
    __syncthreads();

    // ---- Stage E-epi (waves 4-7): c_h, loss3, c_c -> imputations + act staging ----
    if (w >= 4) {
      #pragma unroll
      for (int r = 0; r < 4; r++) {
        int m = quad * 4 + r;
        int ix = m * 68 + colD;
        float al = accP[r];
        float zh = zhbuf[ix], xh = xhbuf[ix];
        float xx = xbuf[ix], mm = mbuf[ix];
        float ch = al * zh + (1.0f - al) * xh;
        loss_acc += fabsf(xx - ch) * mm * invden;
        float cc = mm * xx + (1.0f - mm) * ch;
        imp[((size_t)(b0 + m) * Tt + t) * Dd + colD] = cc;
        act[m * 264 + colD] = f2bf(cc);
      }
    }
    __syncthreads();

    // ---- Stage F: gates = [c_c,m,h_dec] @ [W_ih;W_hh]^T + b; LSTM update (frag-local) ----
    {
      floatx4 a0 = {biasF0, biasF0, biasF0, biasF0};
      floatx4 a1 = {biasF1, biasF1, biasF1, biasF1};
      floatx4 a2 = {biasF2, biasF2, biasF2, biasF2};
      floatx4 a3 = {biasF3, biasF3, biasF3, biasF3};
      #pragma unroll
      for (int ks = 0; ks < 8; ks++) {
        short8 a = *(const short8*)(&act[l15 * 264 + ks * 32 + quad * 8]);
        a0 = __builtin_amdgcn_mfma_f32_16x16x32_bf16(a, wF[ks], a0, 0, 0, 0);
        a1 = __builtin_amdgcn_mfma_f32_16x16x32_bf16(a, wF[8 + ks], a1, 0, 0, 0);
        a2 = __builtin_amdgcn_mfma_f32_16x16x32_bf16(a, wF[16 + ks], a2, 0, 0, 0);
        a3 = __builtin_amdgcn_mfma_f32_16x16x32_bf16(a, wF[24 + ks], a3, 0, 0, 0);
      }
      #pragma unroll
      for (int r = 0; r < 4; r++) {
        float ig = sigmoidf_(a0[r]);
        float fg = sigmoidf_(a1[r]);
        float gg = tanhf_(a2[r]);
        float og = sigmoidf_(a3[r]);
        c_reg[r] = fg * c_reg[r] + ig * gg;
        h_reg[r] = og * tanhf_(c_reg[r]);
      }
    }
  }

  // ---- loss reduction ----
  float s = loss_acc;
  for (int off = 32; off > 0; off >>= 1) s += __shfl_down(s, off, 64);
  if (lane == 0) red[w] = s;
  __syncthreads();
  if (tid == 0) {
    float tot = 0.0f;
    #pragma unroll
    for (int i = 0; i < 8; i++) tot += red[i];
    atomicAdd(&ws[WS_LOSS], tot);
  }
}

// ---------------- kernel 3: finalize loss ----------------
__global__ void final_kernel(const float* __restrict__ ws, float* __restrict__ out) {
  if (threadIdx.x == 0 && blockIdx.x == 0) out[0] = 0.3f * ws[WS_LOSS];
}

extern "C" void kernel_launch(void* const* d_in, const int* in_sizes, int n_in,
                              void* d_out, int out_size, void* d_ws, size_t ws_size,
                              hipStream_t stream) {
  const float* values = (const float*)d_in[0];
  const float* masks  = (const float*)d_in[1];
  const float* deltas = (const float*)d_in[2];
  const float* W_td_h = (const float*)d_in[3];
  const float* b_td_h = (const float*)d_in[4];
  const float* W_td_x = (const float*)d_in[5];
  const float* b_td_x = (const float*)d_in[6];
  const float* W_hist = (const float*)d_in[7];
  const float* b_hist = (const float*)d_in[8];
  const float* W_feat = (const float*)d_in[9];
  const float* b_feat = (const float*)d_in[10];
  const float* W_comb = (const float*)d_in[11];
  const float* b_comb = (const float*)d_in[12];
  const float* W_ih   = (const float*)d_in[13];
  const float* W_hh   = (const float*)d_in[14];
  const float* b_ih   = (const float*)d_in[15];
  const float* b_hh   = (const float*)d_in[16];
  float* out = (float*)d_out;
  float* ws  = (float*)d_ws;   // uses 64 + 312*256 floats ≈ 320 KB

  prep_kernel<<<dim3(N_FRAGS), dim3(256), 0, stream>>>(W_td_h, W_hist, W_feat, W_comb,
                                                       W_ih, W_hh, ws);
  denom_kernel<<<dim3(48 * 16), dim3(256), 0, stream>>>(masks, ws);
  main_kernel<<<dim3(Bb / NB), dim3(NTHR), 0, stream>>>(values, masks, deltas, W_td_x,
                                                        b_td_h, b_td_x, b_hist, b_feat,
                                                        b_comb, b_ih, b_hh, ws, out);
  final_kernel<<<dim3(1), dim3(64), 0, stream>>>(ws, out);
}

// Round 3
// 375.208 us; speedup vs baseline: 5.8900x; 1.0036x over previous
//
#include <hip/hip_runtime.h>
#include <cmath>

// B,T,D,H = 4096,48,64,128
#define Bb 4096
#define Tt 48
#define Dd 64
#define Hh 128
#define NB 16      // batch rows per block (M of MFMA)
#define NTHR 512   // 8 waves

typedef unsigned short ushort_t;
typedef __attribute__((ext_vector_type(8))) short short8;    // 8 bf16 = 4 VGPRs (MFMA A/B frag)
typedef __attribute__((ext_vector_type(4))) float floatx4;   // MFMA C/D frag

// ---- workspace layout (floats) ----
#define WS_DEN   0     // denoms[48]
#define WS_LOSS  48
#define WS_FRAGS 64    // bf16 frag area starts here (16B aligned)
// frag indices (each frag = 64 lanes x 8 bf16 = 512 ushorts = 1 KB)
#define FR_F 0         // 256 frags: gates  [w:8][g:4][ks:8]   K=256 (c_c|m|h)
#define FR_A 256       // 16: W_td_h        [w:8][ks:2]        K=64
#define FR_B 272       // 16: W_hist        [w:4][ks:4]        K=128
#define FR_C 288       // 8 : W_feat masked [w:4][ks:2]        K=64
#define FR_E 296       // 16: W_comb        [w:4][ks:4]        K=128
#define N_FRAGS 312

__device__ __forceinline__ ushort_t f2bf(float x) {   // RNE float->bf16 bits
  unsigned int u = __float_as_uint(x);
  u += 0x7fffu + ((u >> 16) & 1u);
  return (ushort_t)(u >> 16);
}
__device__ __forceinline__ float sigmoidf_(float x) { return 1.0f / (1.0f + __expf(-x)); }
__device__ __forceinline__ float tanhf_(float x) { return 2.0f / (1.0f + __expf(-2.0f * x)) - 1.0f; }

// ---------------- kernel 0: pack weights into per-lane MFMA B-frags (bf16) ----------------
// B-frag layout for mfma_f32_16x16x32_bf16: lane l holds B[k=(l>>4)*8+j][n=l&15], j=0..7
__global__ void prep_kernel(const float* __restrict__ W_td_h, const float* __restrict__ W_hist,
                            const float* __restrict__ W_feat, const float* __restrict__ W_comb,
                            const float* __restrict__ W_ih, const float* __restrict__ W_hh,
                            float* __restrict__ ws) {
  int f = blockIdx.x;                 // one frag per block
  int tid = threadIdx.x;              // 256 threads, 2 elems each
  if (f == 0 && tid < 64) ws[tid] = 0.0f;   // zero denoms + loss
  ushort_t* fb = (ushort_t*)(ws + WS_FRAGS);
  #pragma unroll
  for (int u = 0; u < 2; u++) {
    int e = tid * 2 + u;              // 0..511 = l*8 + j
    int l = e >> 3, j = e & 7;
    int n16 = l & 15;
    int kq = ((l >> 4) << 3) + j;     // quad*8 + j  (0..31)
    float v;
    if (f < 256) {
      int w = f >> 5, g = (f >> 3) & 3, ks = f & 7;
      int n = g * 128 + w * 16 + n16;           // gate row in [512]
      int k = ks * 32 + kq;                     // 0..255: 0-127 -> W_ih, 128-255 -> W_hh
      v = (k < 128) ? W_ih[n * 128 + k] : W_hh[n * 128 + (k - 128)];
    } else if (f < 272) {
      int ff = f - 256, w = ff >> 1, ks = ff & 1;
      int n = w * 16 + n16;                     // 0..127
      v = W_td_h[n * 64 + ks * 32 + kq];
    } else if (f < 288) {
      int ff = f - 272, w = ff >> 2, ks = ff & 3;
      int n = w * 16 + n16;                     // 0..63
      v = W_hist[n * 128 + ks * 32 + kq];
    } else if (f < 296) {
      int ff = f - 288, w = ff >> 1, ks = ff & 1;
      int n = w * 16 + n16;
      int k = ks * 32 + kq;
      v = (n == k) ? 0.0f : W_feat[n * 64 + k];  // zeroed diagonal
    } else {
      int ff = f - 296, w = ff >> 2, ks = ff & 3;
      int n = w * 16 + n16;
      v = W_comb[n * 128 + ks * 32 + kq];       // cols: 0-63 gamma_x, 64-127 m
    }
    fb[f * 512 + e] = f2bf(v);
  }
}

// ---------------- kernel 1: denom_t = sum over [B,D] of masks[:,t,:] ----------------
__global__ void denom_kernel(const float* __restrict__ masks, float* __restrict__ ws) {
  int t = blockIdx.x >> 4;
  int chunk = blockIdx.x & 15;
  int base = chunk * 256;
  int tid = threadIdx.x;
  int j = tid & 63;
  int brow = tid >> 6;
  float s = 0.0f;
  for (int i = 0; i < 64; i++) {
    int b = base + i * 4 + brow;
    s += masks[((size_t)b * Tt + t) * Dd + j];
  }
  for (int off = 32; off > 0; off >>= 1) s += __shfl_down(s, off, 64);
  __shared__ float red[4];
  if ((tid & 63) == 0) red[tid >> 6] = s;
  __syncthreads();
  if (tid == 0) atomicAdd(&ws[WS_DEN + t], red[0] + red[1] + red[2] + red[3]);
}

// ---------------- kernel 2: persistent MFMA recurrence ----------------
__global__ __launch_bounds__(NTHR, 2)
void main_kernel(const float* __restrict__ values, const float* __restrict__ masks,
                 const float* __restrict__ deltas, const float* __restrict__ W_td_x,
                 const float* __restrict__ b_td_h, const float* __restrict__ b_td_x,
                 const float* __restrict__ b_hist, const float* __restrict__ b_feat,
                 const float* __restrict__ b_comb,
                 const float* __restrict__ b_ih, const float* __restrict__ b_hh,
                 float* ws, float* __restrict__ out) {
  // LDS (~28 KB)
  __shared__ __align__(16) ushort_t act[16 * 264];   // bf16 [16][256+8]: c_c | m | h_dec
  __shared__ __align__(16) ushort_t dbuf[16 * 72];   // bf16 d
  __shared__ __align__(16) ushort_t gxbuf[16 * 72];  // bf16 gamma_x
  __shared__ __align__(16) ushort_t xcbuf[16 * 72];  // bf16 x_c
  __shared__ __align__(16) float xmbuf[16 * 132];    // fp32 interleaved [x,m] pairs
  __shared__ __align__(16) float xhbuf[16 * 68];     // fp32 x_h
  __shared__ float red[8];

  int tid = threadIdx.x;
  int w = tid >> 6;            // wave 0..7
  int lane = tid & 63;
  int l15 = lane & 15;
  int quad = lane >> 4;
  int b0 = blockIdx.x * NB;
  const ushort_t* fb = (const ushort_t*)(ws + WS_FRAGS);

  // ---- one-time: all weights into registers (per-wave-private frags) ----
  short8 wF[32];
  #pragma unroll
  for (int g = 0; g < 4; g++)
    #pragma unroll
    for (int ks = 0; ks < 8; ks++)
      wF[g * 8 + ks] = *(const short8*)(fb + (size_t)(FR_F + w * 32 + g * 8 + ks) * 512 + lane * 8);
  short8 wA[2];
  #pragma unroll
  for (int ks = 0; ks < 2; ks++)
    wA[ks] = *(const short8*)(fb + (size_t)(FR_A + w * 2 + ks) * 512 + lane * 8);
  short8 wBE[4];
  short8 wC[2];
  if (w < 4) {
    #pragma unroll
    for (int ks = 0; ks < 4; ks++)
      wBE[ks] = *(const short8*)(fb + (size_t)(FR_B + w * 4 + ks) * 512 + lane * 8);
  } else {
    #pragma unroll
    for (int ks = 0; ks < 4; ks++)
      wBE[ks] = *(const short8*)(fb + (size_t)(FR_E + (w - 4) * 4 + ks) * 512 + lane * 8);
    #pragma unroll
    for (int ks = 0; ks < 2; ks++)
      wC[ks] = *(const short8*)(fb + (size_t)(FR_C + (w - 4) * 2 + ks) * 512 + lane * 8);
  }

  // ---- biases at this lane's owned columns ----
  int colh = w * 16 + l15;           // 0..127 (A cols, F gate cols)
  float biasF0 = b_ih[colh]       + b_hh[colh];
  float biasF1 = b_ih[128 + colh] + b_hh[128 + colh];
  float biasF2 = b_ih[256 + colh] + b_hh[256 + colh];
  float biasF3 = b_ih[384 + colh] + b_hh[384 + colh];
  float biasA  = b_td_h[colh];
  int colD = (w & 3) * 16 + l15;     // 0..63 (B/C/E cols)
  float biasBE = (w < 4) ? b_hist[colD] : b_comb[colD];
  float biasC  = b_feat[colD];       // used by waves 4-7

  // ---- input-load mapping (2 consecutive elements per thread) ----
  int e0 = tid * 2;
  int lb = e0 >> 6, li = e0 & 63;            // li is even
  size_t gbase = ((size_t)(b0 + lb) * Tt) * Dd + li;
  float diag0 = W_td_x[li * 64 + li], diag1 = W_td_x[(li + 1) * 64 + (li + 1)];
  float btx0 = b_td_x[li], btx1 = b_td_x[li + 1];

  // ---- hoisted addresses ----
  int ha[4];                                  // act h-col write addrs (ushort idx)
  float* impp[4];                             // imputation store pointers (advance 64/step)
  #pragma unroll
  for (int r = 0; r < 4; r++) {
    int m = quad * 4 + r;
    ha[r] = m * 264 + 128 + colh;
    impp[r] = out + 1 + (size_t)(b0 + m) * Tt * Dd + colD;
  }

  float h_reg[4] = {0.f, 0.f, 0.f, 0.f};
  float c_reg[4] = {0.f, 0.f, 0.f, 0.f};
  float loss_acc = 0.0f;

  // ---- prefetch t=0 inputs ----
  float2 px = *(const float2*)(values + gbase);
  float2 pm = *(const float2*)(masks + gbase);
  float2 pd = *(const float2*)(deltas + gbase);

  for (int t = 0; t < Tt; t++) {
    __syncthreads();                          // B1: prev step's act/xmbuf reads done
    // ---- stage prefetched inputs to LDS; gamma_x elementwise ----
    *(float4*)(&xmbuf[lb * 132 + 2 * li]) = make_float4(px.x, pm.x, px.y, pm.y);
    *(unsigned int*)(&act[lb * 264 + 64 + li]) =
        (unsigned int)f2bf(pm.x) | ((unsigned int)f2bf(pm.y) << 16);
    *(unsigned int*)(&dbuf[lb * 72 + li]) =
        (unsigned int)f2bf(pd.x) | ((unsigned int)f2bf(pd.y) << 16);
    float g0 = __expf(-fmaxf(pd.x * diag0 + btx0, 0.0f));
    float g1 = __expf(-fmaxf(pd.y * diag1 + btx1, 0.0f));
    *(unsigned int*)(&gxbuf[lb * 72 + li]) =
        (unsigned int)f2bf(g0) | ((unsigned int)f2bf(g1) << 16);
    float invden = 1.0f / (ws[WS_DEN + t] + 1e-5f);
    // ---- init F gate accumulators (persist across slots) ----
    floatx4 a0 = {biasF0, biasF0, biasF0, biasF0};
    floatx4 a1 = {biasF1, biasF1, biasF1, biasF1};
    floatx4 a2 = {biasF2, biasF2, biasF2, biasF2};
    floatx4 a3 = {biasF3, biasF3, biasF3, biasF3};
    // ---- prefetch t+1 inputs (latency hidden across the whole step) ----
    {
      int tn = (t + 1 < Tt) ? (t + 1) : t;
      size_t g = gbase + (size_t)tn * Dd;
      px = *(const float2*)(values + g);
      pm = *(const float2*)(masks + g);
      pd = *(const float2*)(deltas + g);
    }
    __syncthreads();                          // B2: staging visible

    // ---- S1: A (gamma_h) + F m-part (K=64..127). Keep m-frags for E. ----
    short8 mf0 = *(const short8*)(&act[l15 * 264 + 64 + quad * 8]);
    short8 mf1 = *(const short8*)(&act[l15 * 264 + 96 + quad * 8]);
    {
      short8 df0 = *(const short8*)(&dbuf[l15 * 72 + quad * 8]);
      short8 df1 = *(const short8*)(&dbuf[l15 * 72 + 32 + quad * 8]);
      floatx4 accA = {biasA, biasA, biasA, biasA};
      accA = __builtin_amdgcn_mfma_f32_16x16x32_bf16(df0, wA[0], accA, 0, 0, 0);
      accA = __builtin_amdgcn_mfma_f32_16x16x32_bf16(df1, wA[1], accA, 0, 0, 0);
      a0 = __builtin_amdgcn_mfma_f32_16x16x32_bf16(mf0, wF[2],  a0, 0, 0, 0);
      a0 = __builtin_amdgcn_mfma_f32_16x16x32_bf16(mf1, wF[3],  a0, 0, 0, 0);
      a1 = __builtin_amdgcn_mfma_f32_16x16x32_bf16(mf0, wF[10], a1, 0, 0, 0);
      a1 = __builtin_amdgcn_mfma_f32_16x16x32_bf16(mf1, wF[11], a1, 0, 0, 0);
      a2 = __builtin_amdgcn_mfma_f32_16x16x32_bf16(mf0, wF[18], a2, 0, 0, 0);
      a2 = __builtin_amdgcn_mfma_f32_16x16x32_bf16(mf1, wF[19], a2, 0, 0, 0);
      a3 = __builtin_amdgcn_mfma_f32_16x16x32_bf16(mf0, wF[26], a3, 0, 0, 0);
      a3 = __builtin_amdgcn_mfma_f32_16x16x32_bf16(mf1, wF[27], a3, 0, 0, 0);
      #pragma unroll
      for (int r = 0; r < 4; r++) {
        h_reg[r] *= __expf(-fmaxf(accA[r], 0.0f));
        act[ha[r]] = f2bf(h_reg[r]);
      }
    }
    __syncthreads();                          // B3: h_dec staged

    // ---- S2: B (w0-3) / E-mat (w4-7) + F h-part (all). ----
    floatx4 accP = {biasBE, biasBE, biasBE, biasBE};
    {
      short8 hf0 = *(const short8*)(&act[l15 * 264 + 128 + quad * 8]);
      short8 hf1 = *(const short8*)(&act[l15 * 264 + 160 + quad * 8]);
      short8 hf2 = *(const short8*)(&act[l15 * 264 + 192 + quad * 8]);
      short8 hf3 = *(const short8*)(&act[l15 * 264 + 224 + quad * 8]);
      if (w < 4) {
        accP = __builtin_amdgcn_mfma_f32_16x16x32_bf16(hf0, wBE[0], accP, 0, 0, 0);
        accP = __builtin_amdgcn_mfma_f32_16x16x32_bf16(hf1, wBE[1], accP, 0, 0, 0);
        accP = __builtin_amdgcn_mfma_f32_16x16x32_bf16(hf2, wBE[2], accP, 0, 0, 0);
        accP = __builtin_amdgcn_mfma_f32_16x16x32_bf16(hf3, wBE[3], accP, 0, 0, 0);
      } else {
        short8 gx0 = *(const short8*)(&gxbuf[l15 * 72 + quad * 8]);
        short8 gx1 = *(const short8*)(&gxbuf[l15 * 72 + 32 + quad * 8]);
        accP = __builtin_amdgcn_mfma_f32_16x16x32_bf16(gx0, wBE[0], accP, 0, 0, 0);
        accP = __builtin_amdgcn_mfma_f32_16x16x32_bf16(gx1, wBE[1], accP, 0, 0, 0);
        accP = __builtin_amdgcn_mfma_f32_16x16x32_bf16(mf0, wBE[2], accP, 0, 0, 0);
        accP = __builtin_amdgcn_mfma_f32_16x16x32_bf16(mf1, wBE[3], accP, 0, 0, 0);
      }
      a0 = __builtin_amdgcn_mfma_f32_16x16x32_bf16(hf0, wF[4],  a0, 0, 0, 0);
      a0 = __builtin_amdgcn_mfma_f32_16x16x32_bf16(hf1, wF[5],  a0, 0, 0, 0);
      a0 = __builtin_amdgcn_mfma_f32_16x16x32_bf16(hf2, wF[6],  a0, 0, 0, 0);
      a0 = __builtin_amdgcn_mfma_f32_16x16x32_bf16(hf3, wF[7],  a0, 0, 0, 0);
      a1 = __builtin_amdgcn_mfma_f32_16x16x32_bf16(hf0, wF[12], a1, 0, 0, 0);
      a1 = __builtin_amdgcn_mfma_f32_16x16x32_bf16(hf1, wF[13], a1, 0, 0, 0);
      a1 = __builtin_amdgcn_mfma_f32_16x16x32_bf16(hf2, wF[14], a1, 0, 0, 0);
      a1 = __builtin_amdgcn_mfma_f32_16x16x32_bf16(hf3, wF[15], a1, 0, 0, 0);
      a2 = __builtin_amdgcn_mfma_f32_16x16x32_bf16(hf0, wF[20], a2, 0, 0, 0);
      a2 = __builtin_amdgcn_mfma_f32_16x16x32_bf16(hf1, wF[21], a2, 0, 0, 0);
      a2 = __builtin_amdgcn_mfma_f32_16x16x32_bf16(hf2, wF[22], a2, 0, 0, 0);
      a2 = __builtin_amdgcn_mfma_f32_16x16x32_bf16(hf3, wF[23], a2, 0, 0, 0);
      a3 = __builtin_amdgcn_mfma_f32_16x16x32_bf16(hf0, wF[28], a3, 0, 0, 0);
      a3 = __builtin_amdgcn_mfma_f32_16x16x32_bf16(hf1, wF[29], a3, 0, 0, 0);
      a3 = __builtin_amdgcn_mfma_f32_16x16x32_bf16(hf2, wF[30], a3, 0, 0, 0);
      a3 = __builtin_amdgcn_mfma_f32_16x16x32_bf16(hf3, wF[31], a3, 0, 0, 0);
      if (w < 4) {                            // B epilogue: loss1, x_h, x_c
        #pragma unroll
        for (int r = 0; r < 4; r++) {
          int m = quad * 4 + r;
          float2 xm = *(const float2*)(&xmbuf[m * 132 + 2 * colD]);
          float xh = accP[r];
          loss_acc += fabsf(xm.x - xh) * xm.y * invden;
          xhbuf[m * 68 + colD] = xh;
          xcbuf[m * 72 + colD] = f2bf(xm.y * xm.x + (1.0f - xm.y) * xh);
        }
      }
    }
    __syncthreads();                          // B4: x_c, x_h staged

    // ---- S3 (w4-7): C (z_h) + E epilogue, all register-local ----
    if (w >= 4) {
      short8 xc0 = *(const short8*)(&xcbuf[l15 * 72 + quad * 8]);
      short8 xc1 = *(const short8*)(&xcbuf[l15 * 72 + 32 + quad * 8]);
      floatx4 accC = {biasC, biasC, biasC, biasC};
      accC = __builtin_amdgcn_mfma_f32_16x16x32_bf16(xc0, wC[0], accC, 0, 0, 0);
      accC = __builtin_amdgcn_mfma_f32_16x16x32_bf16(xc1, wC[1], accC, 0, 0, 0);
      #pragma unroll
      for (int r = 0; r < 4; r++) {
        int m = quad * 4 + r;
        float2 xm = *(const float2*)(&xmbuf[m * 132 + 2 * colD]);
        float xh = xhbuf[m * 68 + colD];
        float zh = accC[r];
        float al = accP[r];
        loss_acc += fabsf(xm.x - zh) * xm.y * invden;        // loss2
        float ch = al * zh + (1.0f - al) * xh;
        loss_acc += fabsf(xm.x - ch) * xm.y * invden;        // loss3
        float cc = xm.y * xm.x + (1.0f - xm.y) * ch;
        *impp[r] = cc;
        impp[r] += Dd;
        act[m * 264 + colD] = f2bf(cc);
      }
    } else {
      #pragma unroll
      for (int r = 0; r < 4; r++) impp[r] += Dd;   // keep pointers uniform (unused by w<4)
    }
    __syncthreads();                          // B5: c_c staged

    // ---- S5: F c_c-part (K=0..63) + LSTM update ----
    {
      short8 cf0 = *(const short8*)(&act[l15 * 264 + quad * 8]);
      short8 cf1 = *(const short8*)(&act[l15 * 264 + 32 + quad * 8]);
      a0 = __builtin_amdgcn_mfma_f32_16x16x32_bf16(cf0, wF[0],  a0, 0, 0, 0);
      a0 = __builtin_amdgcn_mfma_f32_16x16x32_bf16(cf1, wF[1],  a0, 0, 0, 0);
      a1 = __builtin_amdgcn_mfma_f32_16x16x32_bf16(cf0, wF[8],  a1, 0, 0, 0);
      a1 = __builtin_amdgcn_mfma_f32_16x16x32_bf16(cf1, wF[9],  a1, 0, 0, 0);
      a2 = __builtin_amdgcn_mfma_f32_16x16x32_bf16(cf0, wF[16], a2, 0, 0, 0);
      a2 = __builtin_amdgcn_mfma_f32_16x16x32_bf16(cf1, wF[17], a2, 0, 0, 0);
      a3 = __builtin_amdgcn_mfma_f32_16x16x32_bf16(cf0, wF[24], a3, 0, 0, 0);
      a3 = __builtin_amdgcn_mfma_f32_16x16x32_bf16(cf1, wF[25], a3, 0, 0, 0);
      #pragma unroll
      for (int r = 0; r < 4; r++) {
        float ig = sigmoidf_(a0[r]);
        float fg = sigmoidf_(a1[r]);
        float gg = tanhf_(a2[r]);
        float og = sigmoidf_(a3[r]);
        c_reg[r] = fg * c_reg[r] + ig * gg;
        h_reg[r] = og * tanhf_(c_reg[r]);
      }
    }
  }

  // ---- loss reduction ----
  float s = loss_acc;
  for (int off = 32; off > 0; off >>= 1) s += __shfl_down(s, off, 64);
  if (lane == 0) red[w] = s;
  __syncthreads();
  if (tid == 0) {
    float tot = 0.0f;
    #pragma unroll
    for (int i = 0; i < 8; i++) tot += red[i];
    atomicAdd(&ws[WS_LOSS], tot);
  }
}

// ---------------- kernel 3: finalize loss ----------------
__global__ void final_kernel(const float* __restrict__ ws, float* __restrict__ out) {
  if (threadIdx.x == 0 && blockIdx.x == 0) out[0] = 0.3f * ws[WS_LOSS];
}

extern "C" void kernel_launch(void* const* d_in, const int* in_sizes, int n_in,
                              void* d_out, int out_size, void* d_ws, size_t ws_size,
                              hipStream_t stream) {
  const float* values = (const float*)d_in[0];
  const float* masks  = (const float*)d_in[1];
  const float* deltas = (const float*)d_in[2];
  const float* W_td_h = (const float*)d_in[3];
  const float* b_td_h = (const float*)d_in[4];
  const float* W_td_x = (const float*)d_in[5];
  const float* b_td_x = (const float*)d_in[6];
  const float* W_hist = (const float*)d_in[7];
  const float* b_hist = (const float*)d_in[8];
  const float* W_feat = (const float*)d_in[9];
  const float* b_feat = (const float*)d_in[10];
  const float* W_comb = (const float*)d_in[11];
  const float* b_comb = (const float*)d_in[12];
  const float* W_ih   = (const float*)d_in[13];
  const float* W_hh   = (const float*)d_in[14];
  const float* b_ih   = (const float*)d_in[15];
  const float* b_hh   = (const float*)d_in[16];
  float* out = (float*)d_out;
  float* ws  = (float*)d_ws;   // uses 64 + 312*256 floats ≈ 320 KB

  prep_kernel<<<dim3(N_FRAGS), dim3(256), 0, stream>>>(W_td_h, W_hist, W_feat, W_comb,
                                                       W_ih, W_hh, ws);
  denom_kernel<<<dim3(48 * 16), dim3(256), 0, stream>>>(masks, ws);
  main_kernel<<<dim3(Bb / NB), dim3(NTHR), 0, stream>>>(values, masks, deltas, W_td_x,
                                                        b_td_h, b_td_x, b_hist, b_feat,
                                                        b_comb, b_ih, b_hh, ws, out);
  final_kernel<<<dim3(1), dim3(64), 0, stream>>>(ws, out);
}